// Round 4
// baseline (93.665 us; speedup 1.0000x reference)
//
#include <hip/hip_runtime.h>
#include <float.h>

// ChamferLoss: B=4, N=16384 src, M=4096 verts, fp32.
// loss[b] = (1/N) * sum_n min_m max(||p_bn - v_bm||^2, 0)
//
// d2 = p2 + v2 - 2*dot(p,v); p2 folded out of inner loop. Verts
// pre-transformed to {-2x,-2y,-2z,v2} (float4) in ws by a tiny pre-pass.
// Inner loop reads the vert at a WAVE-UNIFORM address -> scalar pipe
// (s_load_dwordx4), and v_fma_f32 uses the SGPR operand directly: no LDS,
// no bank conflicts, no LDS-pipe contention. Body = 1 s_load + 32 VALU.
// VALU floor: 268M pairs * 4 lane-ops / 78.6 T/s = 13.7 us.

constexpr int B = 4, N = 16384, M = 4096;
constexpr int BN  = B * N;     // 65536 points
constexpr int C   = 32;        // vert chunks per batch
constexpr int VC  = M / C;     // 128 verts per chunk
constexpr int P   = 8;         // points per thread
constexpr int TPB = 256;
constexpr int PPB = TPB * P;   // 2048 points per block
constexpr int PB  = BN / PPB;  // 32 point-blocks
// main grid = PB*C = 1024 blocks -> 4 blocks/CU, 16 waves/CU, zero LDS.

// ws layout: vt (B*M float4 = 256 KB) | partial (C*BN floats = 8 MB)
constexpr size_t VT_F4   = (size_t)B * M;        // float4 count
constexpr size_t PART_OFF = VT_F4 * 4;           // float offset of partial

// Pre-pass: vt[i] = {-2x,-2y,-2z, x^2+y^2+z^2} for each of B*M verts.
__global__ __launch_bounds__(256) void chamfer_pre(
    const float* __restrict__ tv, float4* __restrict__ vt,
    float* __restrict__ out)
{
    int i = blockIdx.x * 256 + threadIdx.x;      // 64 blocks
    if (blockIdx.x == 0 && threadIdx.x < B) out[threadIdx.x] = 0.0f;
    float x = tv[3 * i + 0];
    float y = tv[3 * i + 1];
    float z = tv[3 * i + 2];
    vt[i] = make_float4(-2.0f * x, -2.0f * y, -2.0f * z,
                        fmaf(x, x, fmaf(y, y, z * z)));
}

// Main: block (pb, c) -> 2048 points x verts [c*VC,(c+1)*VC).
// partial[c][point] = min_j(d) + p2  (clamp deferred to reduce).
__global__ __launch_bounds__(TPB) void chamfer_main(
    const float* __restrict__ src, const float4* __restrict__ vt,
    float* __restrict__ partial)
{
    const int blk = blockIdx.x;
    const int c   = blk & (C - 1);
    const int pb  = blk >> 5;          // log2(C) = 5
    const int b   = pb >> 3;           // 8 point-blocks per batch

    // Wave-uniform chunk base -> scalar loads in the inner loop.
    const float4* vchunk = vt + (size_t)b * M + (size_t)c * VC;

    // This thread's 8 consecutive points (96 B, 16B-aligned) as 6 float4.
    const int p0 = pb * PPB + threadIdx.x * P;
    const float4* pv4 = (const float4*)(src + (size_t)p0 * 3);
    float4 q0 = pv4[0], q1 = pv4[1], q2 = pv4[2],
           q3 = pv4[3], q4 = pv4[4], q5 = pv4[5];
    float px[P], py[P], pz[P], mn[P];
    px[0]=q0.x; py[0]=q0.y; pz[0]=q0.z;
    px[1]=q0.w; py[1]=q1.x; pz[1]=q1.y;
    px[2]=q1.z; py[2]=q1.w; pz[2]=q2.x;
    px[3]=q2.y; py[3]=q2.z; pz[3]=q2.w;
    px[4]=q3.x; py[4]=q3.y; pz[4]=q3.z;
    px[5]=q3.w; py[5]=q4.x; pz[5]=q4.y;
    px[6]=q4.z; py[6]=q4.w; pz[6]=q5.x;
    px[7]=q5.y; py[7]=q5.z; pz[7]=q5.w;
#pragma unroll
    for (int p = 0; p < P; ++p) mn[p] = FLT_MAX;

    // Inner loop: 1 s_load_dwordx4 (uniform addr, scalar cache) + 32 VALU.
#pragma unroll 8
    for (int j = 0; j < VC; ++j) {
        float4 v = vchunk[j];
#pragma unroll
        for (int p = 0; p < P; ++p) {
            float d = fmaf(v.x, px[p], fmaf(v.y, py[p], fmaf(v.z, pz[p], v.w)));
            mn[p] = fminf(mn[p], d);
        }
    }

    // partial layout [chunk][point]: this thread's 8 results contiguous.
    float o[P];
#pragma unroll
    for (int p = 0; p < P; ++p) {
        float p2 = fmaf(px[p], px[p], fmaf(py[p], py[p], pz[p] * pz[p]));
        o[p] = mn[p] + p2;
    }
    float4* dst = (float4*)(partial + (size_t)c * BN + p0);
    dst[0] = make_float4(o[0], o[1], o[2], o[3]);
    dst[1] = make_float4(o[4], o[5], o[6], o[7]);
}

// Reduce: 256 blocks x 256 threads, one point/thread. Min over C chunk
// partials (lane-coalesced per chunk), clamp, block-sum, atomicAdd.
__global__ __launch_bounds__(256) void chamfer_reduce(
    const float* __restrict__ partial, float* __restrict__ out)
{
    const int p = blockIdx.x * 256 + threadIdx.x;
    const int b = blockIdx.x >> 6;     // 64 blocks per batch

    float m = FLT_MAX;
#pragma unroll
    for (int c = 0; c < C; ++c) m = fminf(m, partial[(size_t)c * BN + p]);
    float sum = fmaxf(m, 0.0f);

    for (int off = 32; off > 0; off >>= 1)
        sum += __shfl_down(sum, off, 64);
    __shared__ float acc[4];
    if ((threadIdx.x & 63) == 0) acc[threadIdx.x >> 6] = sum;
    __syncthreads();
    if (threadIdx.x == 0) {
        float s = acc[0] + acc[1] + acc[2] + acc[3];
        atomicAdd(&out[b], s * (1.0f / N));
    }
}

extern "C" void kernel_launch(void* const* d_in, const int* in_sizes, int n_in,
                              void* d_out, int out_size, void* d_ws, size_t ws_size,
                              hipStream_t stream) {
    const float* src = (const float*)d_in[0];  // (B, N, 3) fp32
    const float* tv  = (const float*)d_in[1];  // (B, M, 3) fp32
    float* out = (float*)d_out;                // (B,) fp32
    float* ws  = (float*)d_ws;
    float4* vt = (float4*)ws;                  // 256 KB
    float* partial = ws + PART_OFF;            // 8 MB

    chamfer_pre   <<<(B * M) / 256, 256, 0, stream>>>(tv, vt, out);
    chamfer_main  <<<PB * C, TPB, 0, stream>>>(src, vt, partial);
    chamfer_reduce<<<256, 256, 0, stream>>>(partial, out);
}

// Round 5
// 83.318 us; speedup vs baseline: 1.1242x; 1.1242x over previous
//
#include <hip/hip_runtime.h>
#include <float.h>

// ChamferLoss: B=4, N=16384 src, M=4096 verts, fp32.
// loss[b] = (1/N) * sum_n min_m max(||p_bn - v_bm||^2, 0)
//
// d2 = p2 + v2 - 2*dot(p,v); p2 folded out of the inner loop (constant per
// point; clamp commutes with min). Verts pre-transformed in-block to
// {-2x,-2y,-2z,v2} in LDS -> inner body = 3 FMA + 1 min per pair.
// VALU floor: 268M pairs * 4 lane-ops / 78.6 T/s = 13.7 us.
//
// P=16 points/thread: 64 VALU instrs per broadcast ds_read_b128 -> LDS pipe
// ~37% of the VALU-bound rate (was ~75% at P=8), 16 independent min chains.

constexpr int B = 4, N = 16384, M = 4096;
constexpr int BN  = B * N;     // 65536 points
constexpr int C   = 32;        // vert chunks per batch
constexpr int VC  = M / C;     // 128 verts per chunk
constexpr int P   = 16;        // points per thread
constexpr int TPB = 256;
constexpr int PPB = TPB * P;   // 4096 points per block
constexpr int PB  = BN / PPB;  // 16 point-blocks
// grid = PB*C = 512 blocks -> 2 blocks/CU, 2 waves/SIMD, 2 KB LDS.

__global__ __launch_bounds__(TPB) void chamfer_main(
    const float* __restrict__ src, const float* __restrict__ tv,
    float* __restrict__ partial, float* __restrict__ out)
{
    __shared__ float4 lv[VC];
    const int blk = blockIdx.x;
    const int c   = blk & (C - 1);
    const int pb  = blk >> 5;          // log2(C) = 5
    const int b   = pb >> 2;           // 4 point-blocks per batch

    // Zero output (poisoned each launch); main completes before reduce.
    if (blk == 0 && threadIdx.x < B) out[threadIdx.x] = 0.0f;

    // Stage this chunk's 128 verts, transformed to {-2x,-2y,-2z,v2}.
    const float* vsrc = tv + ((size_t)b * M + (size_t)c * VC) * 3;
    if (threadIdx.x < VC) {
        int i = threadIdx.x;
        float x = vsrc[3 * i + 0];
        float y = vsrc[3 * i + 1];
        float z = vsrc[3 * i + 2];
        lv[i] = make_float4(-2.0f * x, -2.0f * y, -2.0f * z,
                            fmaf(x, x, fmaf(y, y, z * z)));
    }

    // This thread's 16 consecutive points (192 B, 16B-aligned) as 12 float4.
    const int p0 = pb * PPB + threadIdx.x * P;
    const float4* pv4 = (const float4*)(src + (size_t)p0 * 3);
    float px[P], py[P], pz[P], mn[P];
#pragma unroll
    for (int k = 0; k < 4; ++k) {
        float4 a = pv4[3 * k + 0], bq = pv4[3 * k + 1], cq = pv4[3 * k + 2];
        px[4*k+0]=a.x;  py[4*k+0]=a.y;  pz[4*k+0]=a.z;
        px[4*k+1]=a.w;  py[4*k+1]=bq.x; pz[4*k+1]=bq.y;
        px[4*k+2]=bq.z; py[4*k+2]=bq.w; pz[4*k+2]=cq.x;
        px[4*k+3]=cq.y; py[4*k+3]=cq.z; pz[4*k+3]=cq.w;
    }
#pragma unroll
    for (int p = 0; p < P; ++p) mn[p] = FLT_MAX;

    __syncthreads();

    // Inner loop: 1 broadcast ds_read_b128 (all lanes same addr, conflict
    // free) + 16 * (3 FMA + 1 min). Unroll 4 -> 4 outstanding reads, 256
    // VALU instrs (512 issue cyc) per body.
#pragma unroll 4
    for (int j = 0; j < VC; ++j) {
        float4 v = lv[j];
#pragma unroll
        for (int p = 0; p < P; ++p) {
            float d = fmaf(v.x, px[p], fmaf(v.y, py[p], fmaf(v.z, pz[p], v.w)));
            mn[p] = fminf(mn[p], d);
        }
    }

    // partial[c][point]: this thread's 16 results contiguous (4 x dwordx4).
    float4* dst = (float4*)(partial + (size_t)c * BN + p0);
#pragma unroll
    for (int k = 0; k < 4; ++k) {
        float o[4];
#pragma unroll
        for (int u = 0; u < 4; ++u) {
            int p = 4 * k + u;
            float p2 = fmaf(px[p], px[p], fmaf(py[p], py[p], pz[p] * pz[p]));
            o[u] = mn[p] + p2;
        }
        dst[k] = make_float4(o[0], o[1], o[2], o[3]);
    }
}

// Reduce: 256 blocks x 256 threads, one point/thread. Min over C chunk
// partials (lane-coalesced per chunk), clamp, block-sum, atomicAdd.
__global__ __launch_bounds__(256) void chamfer_reduce(
    const float* __restrict__ partial, float* __restrict__ out)
{
    const int p = blockIdx.x * 256 + threadIdx.x;
    const int b = blockIdx.x >> 6;     // 64 blocks per batch

    float m = FLT_MAX;
#pragma unroll
    for (int c = 0; c < C; ++c) m = fminf(m, partial[(size_t)c * BN + p]);
    float sum = fmaxf(m, 0.0f);

    for (int off = 32; off > 0; off >>= 1)
        sum += __shfl_down(sum, off, 64);
    __shared__ float acc[4];
    if ((threadIdx.x & 63) == 0) acc[threadIdx.x >> 6] = sum;
    __syncthreads();
    if (threadIdx.x == 0) {
        float s = acc[0] + acc[1] + acc[2] + acc[3];
        atomicAdd(&out[b], s * (1.0f / N));
    }
}

extern "C" void kernel_launch(void* const* d_in, const int* in_sizes, int n_in,
                              void* d_out, int out_size, void* d_ws, size_t ws_size,
                              hipStream_t stream) {
    const float* src = (const float*)d_in[0];  // (B, N, 3) fp32
    const float* tv  = (const float*)d_in[1];  // (B, M, 3) fp32
    float* out = (float*)d_out;                // (B,) fp32
    float* partial = (float*)d_ws;             // C*BN floats = 8 MB scratch

    chamfer_main  <<<PB * C, TPB, 0, stream>>>(src, tv, partial, out);
    chamfer_reduce<<<256, 256, 0, stream>>>(partial, out);
}

// Round 6
// 74.507 us; speedup vs baseline: 1.2571x; 1.1183x over previous
//
#include <hip/hip_runtime.h>
#include <float.h>

// ChamferLoss via MFMA: B=4, N=16384 src, M=4096 verts, fp32 in/out.
// loss[b] = (1/N) * sum_n min_m max(||p_bn - v_bm||^2, 0)
//
// d2 = pp + (v2 - 2 p.v). The bracket is computed on the MATRIX pipe with a
// split-bf16 encoding packed into K=16 of mfma_f32_32x32x16_bf16:
//   A row (point):  [ph x3, pl x3, ph x3, 1, 1, 0...]
//   B col (vert):   [-2vh x3, -2vh x3, -2vl x3, v2h, v2l, 0...]
//   dot = v2 - 2(ph.vh + pl.vh + ph.vl) ~= v2 - 2 p.v   (err ~2^-16 |p||v|)
// bf16xbf16 products are exact in fp32; errors wash out in the 16384-point
// mean. Running min per C-register slot across vert tiles; cross-lane min
// done via an LDS transpose in the epilogue. pp added in the reduce kernel.

typedef __bf16 bf16x8 __attribute__((ext_vector_type(8)));
typedef float  f32x16 __attribute__((ext_vector_type(16)));

constexpr int B = 4, N = 16384, M = 4096;
constexpr int BN = B * N;
constexpr int CHUNK_V = 2048;            // verts per chunk (64 KB of B-frags)
constexpr int NCHUNK = M / CHUNK_V;      // 2
constexpr int TILES = CHUNK_V / 32;      // 64 vert tiles per chunk
constexpr int TPB = 256;                 // 4 waves
constexpr int PPB = 256;                 // points per block (wave: 2 tiles)
constexpr int PBLK = BN / PPB;           // 256 point-blocks
constexpr size_t BFRAG_BYTES = (size_t)B * M * 32;   // 512 KB in ws

// ---- Pre-pass: build B-fragments in exact LDS/frag order, zero out[]. ----
// Vert m of batch b -> 16 bf16 K-values; storage byte offset:
//   b*131072 + chunk*65536 + tile*1024 + khalf*512 + col*16 + j*2
__global__ __launch_bounds__(256) void chamfer_pre(
    const float* __restrict__ tv, unsigned char* __restrict__ bfr,
    float* __restrict__ out)
{
    if (blockIdx.x == 0 && threadIdx.x < B) out[threadIdx.x] = 0.0f;
    int i = blockIdx.x * 256 + threadIdx.x;      // 0..B*M-1
    int b = i >> 12;                             // /M
    int m = i & (M - 1);
    float x = tv[3 * i + 0], y = tv[3 * i + 1], z = tv[3 * i + 2];
    __bf16 xh = (__bf16)x, yh = (__bf16)y, zh = (__bf16)z;
    float xhf = (float)xh, yhf = (float)yh, zhf = (float)zh;
    __bf16 xl = (__bf16)(x - xhf), yl = (__bf16)(y - yhf), zl = (__bf16)(z - zhf);
    float v2 = fmaf(x, x, fmaf(y, y, z * z));
    __bf16 v2h = (__bf16)v2;
    __bf16 v2l = (__bf16)(v2 - (float)v2h);
    __bf16 zero = (__bf16)0.0f;

    bf16x8 h0, h1;
    h0[0] = (__bf16)(-2.0f * xhf); h0[1] = (__bf16)(-2.0f * yhf);
    h0[2] = (__bf16)(-2.0f * zhf);
    h0[3] = h0[0]; h0[4] = h0[1]; h0[5] = h0[2];
    h0[6] = (__bf16)(-2.0f * (float)xl); h0[7] = (__bf16)(-2.0f * (float)yl);
    h1[0] = (__bf16)(-2.0f * (float)zl); h1[1] = v2h; h1[2] = v2l;
    h1[3] = zero; h1[4] = zero; h1[5] = zero; h1[6] = zero; h1[7] = zero;

    int chunk = m >> 11, local = m & 2047, tile = local >> 5, c = m & 31;
    size_t base = (size_t)b * 131072 + (size_t)chunk * 65536 + tile * 1024 + c * 16;
    *(bf16x8*)(bfr + base)       = h0;
    *(bf16x8*)(bfr + base + 512) = h1;
}

// ---- Main: 512 blocks = 256 point-blocks x 2 chunks, 2 blocks/CU. ----
// Wave w owns 2 point tiles (64 pts); one B-frag ds_read feeds 2 MFMAs.
// partial[chunk][point] = min over chunk verts of (v2 - 2 p.v).
__global__ __launch_bounds__(TPB) void chamfer_mfma(
    const float* __restrict__ src, const unsigned char* __restrict__ bfr,
    float* __restrict__ partial)
{
    __shared__ uint4 lds4[4096];                 // 64 KB (B-frags, then epi)
    char* ldsc = (char*)lds4;
    const int blk   = blockIdx.x;
    const int chunk = blk & 1;
    const int pblk  = blk >> 1;                  // 0..255
    const int b     = pblk >> 6;                 // 64 point-blocks per batch
    const int t     = threadIdx.x;
    const int w     = t >> 6, L = t & 63;
    const int half  = L >> 5, c = L & 31;

    // Stage 64 KB of pre-built B-frags (identity copy, L2-hot).
    const uint4* gsrc = (const uint4*)(bfr + (size_t)b * 131072 + (size_t)chunk * 65536);
#pragma unroll
    for (int i = 0; i < 16; ++i) lds4[i * 256 + t] = gsrc[i * 256 + t];

    // Build A-frags for this wave's two point tiles.
    // A layout (32x32x16): lane holds row m = L&31, k = (L>>5)*8 + j.
    const int gpa = pblk * 256 + w * 64 + c;     // tile a point
    const int gpb = gpa + 32;                    // tile b point
    float ax = src[3*gpa], ay = src[3*gpa+1], az = src[3*gpa+2];
    float bx = src[3*gpb], by = src[3*gpb+1], bz = src[3*gpb+2];
    __bf16 one = (__bf16)1.0f, zero = (__bf16)0.0f;
    bf16x8 aA, aB;
    {
        __bf16 xh=(__bf16)ax, yh=(__bf16)ay, zh=(__bf16)az;
        __bf16 xl=(__bf16)(ax-(float)xh), yl=(__bf16)(ay-(float)yh), zl=(__bf16)(az-(float)zh);
        if (half == 0) { aA[0]=xh; aA[1]=yh; aA[2]=zh; aA[3]=xl; aA[4]=yl; aA[5]=zl; aA[6]=xh; aA[7]=yh; }
        else { aA[0]=zh; aA[1]=one; aA[2]=one; aA[3]=zero; aA[4]=zero; aA[5]=zero; aA[6]=zero; aA[7]=zero; }
    }
    {
        __bf16 xh=(__bf16)bx, yh=(__bf16)by, zh=(__bf16)bz;
        __bf16 xl=(__bf16)(bx-(float)xh), yl=(__bf16)(by-(float)yh), zl=(__bf16)(bz-(float)zh);
        if (half == 0) { aB[0]=xh; aB[1]=yh; aB[2]=zh; aB[3]=xl; aB[4]=yl; aB[5]=zl; aB[6]=xh; aB[7]=yh; }
        else { aB[0]=zh; aB[1]=one; aB[2]=one; aB[3]=zero; aB[4]=zero; aB[5]=zero; aB[6]=zero; aB[7]=zero; }
    }

    __syncthreads();

    f32x16 mnA, mnB, zeroC;
#pragma unroll
    for (int r = 0; r < 16; ++r) { mnA[r] = FLT_MAX; mnB[r] = FLT_MAX; zeroC[r] = 0.0f; }

    // B-frag read: lane L -> 16 B at tile*1024 + (L>>5)*512 + (L&31)*16.
    const int laneoff = half * 512 + c * 16;
#pragma unroll 8
    for (int tl = 0; tl < TILES; ++tl) {
        bf16x8 bf = *(const bf16x8*)(ldsc + tl * 1024 + laneoff);
        f32x16 Ca = __builtin_amdgcn_mfma_f32_32x32x16_bf16(aA, bf, zeroC, 0, 0, 0);
        f32x16 Cb = __builtin_amdgcn_mfma_f32_32x32x16_bf16(aB, bf, zeroC, 0, 0, 0);
#pragma unroll
        for (int r = 0; r < 16; ++r) {
            mnA[r] = fminf(mnA[r], Ca[r]);
            mnB[r] = fminf(mnB[r], Cb[r]);
        }
    }

    __syncthreads();                             // done with B-frags in LDS

    // Epilogue: C/D layout row=(r&3)+8*(r>>2)+4*half, col=c. Transpose via
    // LDS [8 tiles][32 rows][36 pad] then min across the 32 vert-classes.
    float* epi = (float*)ldsc;
    const int ta = w * 2, tb = ta + 1;
#pragma unroll
    for (int r = 0; r < 16; ++r) {
        int row = (r & 3) + 8 * (r >> 2) + 4 * half;
        epi[(ta * 32 + row) * 36 + c] = mnA[r];
        epi[(tb * 32 + row) * 36 + c] = mnB[r];
    }
    __syncthreads();

    // Thread t -> block-point t (tile t>>5, row t&31): min over 32 classes.
    const float4* rowp = (const float4*)(epi + t * 36);
    float4 q0 = rowp[0], q1 = rowp[1], q2 = rowp[2], q3 = rowp[3];
    float4 q4 = rowp[4], q5 = rowp[5], q6 = rowp[6], q7 = rowp[7];
    float m01 = fminf(fminf(fminf(q0.x,q0.y),fminf(q0.z,q0.w)),
                      fminf(fminf(q1.x,q1.y),fminf(q1.z,q1.w)));
    float m23 = fminf(fminf(fminf(q2.x,q2.y),fminf(q2.z,q2.w)),
                      fminf(fminf(q3.x,q3.y),fminf(q3.z,q3.w)));
    float m45 = fminf(fminf(fminf(q4.x,q4.y),fminf(q4.z,q4.w)),
                      fminf(fminf(q5.x,q5.y),fminf(q5.z,q5.w)));
    float m67 = fminf(fminf(fminf(q6.x,q6.y),fminf(q6.z,q6.w)),
                      fminf(fminf(q7.x,q7.y),fminf(q7.z,q7.w)));
    float mall = fminf(fminf(m01, m23), fminf(m45, m67));
    partial[(size_t)chunk * BN + pblk * 256 + t] = mall;
}

// ---- Reduce: min over chunks, + pp, clamp, per-batch mean. ----
__global__ __launch_bounds__(256) void chamfer_reduce(
    const float* __restrict__ partial, const float* __restrict__ src,
    float* __restrict__ out)
{
    const int p = blockIdx.x * 256 + threadIdx.x;
    const int b = blockIdx.x >> 6;               // 64 blocks per batch
    float m = fminf(partial[p], partial[(size_t)BN + p]);
    float x = src[3*p], y = src[3*p+1], z = src[3*p+2];
    float pp = fmaf(x, x, fmaf(y, y, z * z));
    float sum = fmaxf(m + pp, 0.0f);

    for (int off = 32; off > 0; off >>= 1)
        sum += __shfl_down(sum, off, 64);
    __shared__ float acc[4];
    if ((threadIdx.x & 63) == 0) acc[threadIdx.x >> 6] = sum;
    __syncthreads();
    if (threadIdx.x == 0) {
        float s = acc[0] + acc[1] + acc[2] + acc[3];
        atomicAdd(&out[b], s * (1.0f / N));
    }
}

extern "C" void kernel_launch(void* const* d_in, const int* in_sizes, int n_in,
                              void* d_out, int out_size, void* d_ws, size_t ws_size,
                              hipStream_t stream) {
    const float* src = (const float*)d_in[0];    // (B, N, 3) fp32
    const float* tv  = (const float*)d_in[1];    // (B, M, 3) fp32
    float* out = (float*)d_out;                  // (B,) fp32
    unsigned char* bfr = (unsigned char*)d_ws;   // 512 KB B-frags
    float* partial = (float*)((char*)d_ws + BFRAG_BYTES);  // 512 KB

    chamfer_pre   <<<(B * M) / 256, 256, 0, stream>>>(tv, bfr, out);
    chamfer_mfma  <<<PBLK * NCHUNK, TPB, 0, stream>>>(src, bfr, partial);
    chamfer_reduce<<<BN / 256, 256, 0, stream>>>(partial, src, out);
}